// Round 20
// baseline (271.125 us; speedup 1.0000x reference)
//
#include <hip/hip_runtime.h>
#include <hip/hip_bf16.h>

namespace {
constexpr int S = 2048;
constexpr int D = 64;
constexpr float QSCALE = 0.18033688011112042f;  // (1/sqrt(64)) * log2(e)

using f32x4 = __attribute__((ext_vector_type(4))) float;
using bf16x8 = __attribute__((ext_vector_type(8))) short;

__device__ __forceinline__ short f2bf(float f) {
  return __builtin_bit_cast(short, __float2bfloat16(f));  // native RNE cvt
}
__device__ __forceinline__ float bf2f(unsigned short s) {
  return __builtin_bit_cast(float, (unsigned)s << 16);
}
#if __has_builtin(__builtin_amdgcn_exp2f)
__device__ __forceinline__ float exp2_fast(float x) { return __builtin_amdgcn_exp2f(x); }
#else
__device__ __forceinline__ float exp2_fast(float x) { return exp2f(x); }
#endif

__device__ __forceinline__ void bar_lds() {  // lgkm-only barrier: vmem prefetch stays in flight
  asm volatile("s_waitcnt lgkmcnt(0)" ::: "memory");
  __builtin_amdgcn_s_barrier();
}
}  // namespace

// r19 (268.7 us) + zero-fill as 1KB wave-contiguous runs (64 lanes x 16B on ONE
// row per instruction; row's zero-span [NT*64,2048) is sequential in memory).
// Loop A and loop B byte-identical to r19. 40KB LDS -> 4 blocks/CU.
__global__ __launch_bounds__(256, 4) void attn_fused(const float* __restrict__ qg,
                                                     const float* __restrict__ kg,
                                                     const float* __restrict__ vg,
                                                     float* __restrict__ outg) {
  __shared__ short kbuf[2][64 * 64];   // K[j][d] bf16, XOR-swizzled, dbuf
  __shared__ short vbuf[2][64 * 64];   // V^T[d][j] bf16, XOR-swizzled, dbuf
  __shared__ short pscr[4][16 * 64];   // per-wave p~ redistribution scratch

  const int tid = threadIdx.x;
  const int w = tid >> 6, lane = tid & 63, lg = lane >> 4, lr = lane & 15;

  // XCD-chunked block map + long/short qt interleave for co-resident balance
  const int u = blockIdx.x;
  const int logical = (u & 7) * 256 + (u >> 3);  // 2048 % 8 == 0
  const int bh = logical >> 5;
  const int uu = logical & 31;
  const int qt = (uu & 1) ? (31 - (uu >> 1)) : (uu >> 1);
  const int qrow0 = qt * 64;
  const int NT = qt + 1;

  const size_t bh_off = (size_t)bh * S * D;
  float* const og = outg;
  float* const a_base = outg + (size_t)64 * S * D + (size_t)bh * S * S;
  const int asw = (lr & 7) << 3;

  const int igl = qrow0 + w * 16 + lr;  // this lane's q-row (QK col i / p row)

  // ---- zero tiles (j >= NT*64) FIRST: per instruction, 64 lanes write 1KB
  // contiguous on ONE row; rows swept per wave (w*16..w*16+15) ----
  {
    const int zc0 = NT * 64;
    const f32x4 z = {0.f, 0.f, 0.f, 0.f};
    for (int rr = 0; rr < 16; ++rr) {
      float* const zrow = a_base + (size_t)(qrow0 + w * 16 + rr) * S;
      for (int zc = zc0 + lane * 4; zc < S; zc += 256) {
        __builtin_nontemporal_store(z, (f32x4*)(zrow + zc));
      }
    }
  }

  // ---- Q B-fragment (col i = lr-row of this wave, k = d), QSCALE folded ----
  bf16x8 qf[2];
#pragma unroll
  for (int kh = 0; kh < 2; ++kh) {
    const float* qp = qg + bh_off + (size_t)igl * D + kh * 32 + lg * 8;
    f32x4 x0 = *(const f32x4*)(qp);
    f32x4 x1 = *(const f32x4*)(qp + 4);
    bf16x8 f;
#pragma unroll
    for (int e = 0; e < 4; ++e) {
      f[e] = f2bf(x0[e] * QSCALE);
      f[e + 4] = f2bf(x1[e] * QSCALE);
    }
    qf[kh] = f;
  }

  const int krow = tid >> 2, kc = (tid & 3) * 16;
  const int kswz = (krow & 7) << 3;
  const int vj = tid & 63, vd0 = (tid >> 6) * 16;

  // =========================== loop A: l + O(unnormalized) ===========================
  f32x4 ka[4], va[4];
  {
    const float* kp = kg + bh_off + (size_t)krow * D + kc;
#pragma unroll
    for (int i = 0; i < 4; ++i) ka[i] = *(const f32x4*)(kp + i * 4);
    const float* vp = vg + bh_off + (size_t)vj * D + vd0;
#pragma unroll
    for (int i = 0; i < 4; ++i) va[i] = *(const f32x4*)(vp + i * 4);
  }
  {  // stage tile 0
    bf16x8 kb;
#pragma unroll
    for (int e = 0; e < 4; ++e) { kb[e] = f2bf(ka[0][e]); kb[e + 4] = f2bf(ka[1][e]); }
    *(bf16x8*)(&kbuf[0][(krow * 64 + kc) ^ kswz]) = kb;
#pragma unroll
    for (int e = 0; e < 4; ++e) { kb[e] = f2bf(ka[2][e]); kb[e + 4] = f2bf(ka[3][e]); }
    *(bf16x8*)(&kbuf[0][(krow * 64 + kc + 8) ^ kswz]) = kb;
#pragma unroll
    for (int i = 0; i < 4; ++i)
#pragma unroll
      for (int e = 0; e < 4; ++e) {
        const int d = vd0 + i * 4 + e;
        vbuf[0][(d * 64 + vj) ^ ((d & 7) << 3)] = f2bf(va[i][e]);
      }
  }
  bar_lds();

  float l_acc = 0.f;
  f32x4 oacc[4];
#pragma unroll
  for (int dg = 0; dg < 4; ++dg) oacc[dg] = (f32x4){0.f, 0.f, 0.f, 0.f};

  for (int kt = 0; kt < NT; ++kt) {
    const int cur = kt & 1;
    if (kt + 1 < NT) {  // prefetch next K/V tiles into regs
      const float* kp = kg + bh_off + (size_t)((kt + 1) * 64 + krow) * D + kc;
#pragma unroll
      for (int i = 0; i < 4; ++i) ka[i] = *(const f32x4*)(kp + i * 4);
      const float* vp = vg + bh_off + (size_t)((kt + 1) * 64 + vj) * D + vd0;
#pragma unroll
      for (int i = 0; i < 4; ++i) va[i] = *(const f32x4*)(vp + i * 4);
    }

    // QK^T: D[j][i], lane col i = lr, rows j = jb*16 + lg*4 + r
    f32x4 sacc[4];
#pragma unroll
    for (int jb = 0; jb < 4; ++jb) sacc[jb] = (f32x4){0.f, 0.f, 0.f, 0.f};
#pragma unroll
    for (int kh = 0; kh < 2; ++kh) {
#pragma unroll
      for (int jb = 0; jb < 4; ++jb) {
        bf16x8 kf = *(const bf16x8*)(&kbuf[cur][((jb * 16 + lr) * 64 + kh * 32 + lg * 8) ^ asw]);
        sacc[jb] = __builtin_amdgcn_mfma_f32_16x16x32_bf16(kf, qf[kh], sacc[jb], 0, 0, 0);
      }
    }

    // p~ = exp2(s) (masked on diagonal tile); accumulate l; pscr for PV
    const bool diag = (kt == NT - 1);
#pragma unroll
    for (int jb = 0; jb < 4; ++jb) {
      short4 ps;
#pragma unroll
      for (int r = 0; r < 4; ++r) {
        const int jgl = kt * 64 + jb * 16 + lg * 4 + r;
        float pt = exp2_fast(sacc[jb][r]);
        if (diag && jgl > igl) pt = 0.f;
        l_acc += pt;
        ((short*)&ps)[r] = f2bf(pt);
      }
      *(short4*)(&pscr[w][(lr * 64 + jb * 16 + lg * 4) ^ asw]) = ps;
    }

    // PV: O[i][d] += p~ V (pscr same-wave)
#pragma unroll
    for (int ks = 0; ks < 2; ++ks) {
      bf16x8 pa = *(const bf16x8*)(&pscr[w][(lr * 64 + ks * 32 + lg * 8) ^ asw]);
#pragma unroll
      for (int dg = 0; dg < 4; ++dg) {
        bf16x8 vb = *(const bf16x8*)(&vbuf[cur][((dg * 16 + lr) * 64 + ks * 32 + lg * 8) ^ asw]);
        oacc[dg] = __builtin_amdgcn_mfma_f32_16x16x32_bf16(pa, vb, oacc[dg], 0, 0, 0);
      }
    }

    if (kt + 1 < NT) {  // stage next tile into the other buffers
      bf16x8 kb;
#pragma unroll
      for (int e = 0; e < 4; ++e) { kb[e] = f2bf(ka[0][e]); kb[e + 4] = f2bf(ka[1][e]); }
      *(bf16x8*)(&kbuf[cur ^ 1][(krow * 64 + kc) ^ kswz]) = kb;
#pragma unroll
      for (int e = 0; e < 4; ++e) { kb[e] = f2bf(ka[2][e]); kb[e + 4] = f2bf(ka[3][e]); }
      *(bf16x8*)(&kbuf[cur ^ 1][(krow * 64 + kc + 8) ^ kswz]) = kb;
#pragma unroll
      for (int i = 0; i < 4; ++i)
#pragma unroll
        for (int e = 0; e < 4; ++e) {
          const int d = vd0 + i * 4 + e;
          vbuf[cur ^ 1][(d * 64 + vj) ^ ((d & 7) << 3)] = f2bf(va[i][e]);
        }
    }
    bar_lds();
  }

  // ---- rl: reduce partials across lg; lane then holds rl for its row igl ----
  l_acc += __shfl_xor(l_acc, 16, 64);
  l_acc += __shfl_xor(l_acc, 32, 64);
  const float rlA = 1.f / l_acc;

  // O rescale needs rl at rows w*16+lg*4+r: bounce via per-wave pscr region
  {
    float* const rlv = (float*)(&pscr[w][0]);
    if (lane < 16) rlv[lr] = rlA;
    asm volatile("s_waitcnt lgkmcnt(0)" ::: "memory");  // same-wave write->read
#pragma unroll
    for (int dg = 0; dg < 4; ++dg) {
#pragma unroll
      for (int r = 0; r < 4; ++r) {
        const int il = qrow0 + w * 16 + lg * 4 + r;
        og[bh_off + (size_t)il * D + dg * 16 + lr] = oacc[dg][r] * rlv[lg * 4 + r];
      }
    }
  }

  // ====== loop B: normalized a via pscr transpose -> 256B-contiguous NT stores ======
  {
    const float* kp = kg + bh_off + (size_t)krow * D + kc;
#pragma unroll
    for (int i = 0; i < 4; ++i) ka[i] = *(const f32x4*)(kp + i * 4);
  }
  {  // stage tile 0 (A-loop reads of kbuf[0] finished at A's last barrier)
    bf16x8 kb;
#pragma unroll
    for (int e = 0; e < 4; ++e) { kb[e] = f2bf(ka[0][e]); kb[e + 4] = f2bf(ka[1][e]); }
    *(bf16x8*)(&kbuf[0][(krow * 64 + kc) ^ kswz]) = kb;
#pragma unroll
    for (int e = 0; e < 4; ++e) { kb[e] = f2bf(ka[2][e]); kb[e + 4] = f2bf(ka[3][e]); }
    *(bf16x8*)(&kbuf[0][(krow * 64 + kc + 8) ^ kswz]) = kb;
  }
  bar_lds();

  const int i2 = (lane >> 4);        // row-subgroup for the store phase
  const int c2 = (lane & 15) * 4;    // 16 lanes x f32x4 = full 64-col tile row
  for (int kt = 0; kt < NT; ++kt) {
    const int cur = kt & 1;
    if (kt + 1 < NT) {  // prefetch next K tile (issued BEFORE this tile's stores)
      const float* kp = kg + bh_off + (size_t)((kt + 1) * 64 + krow) * D + kc;
#pragma unroll
      for (int i = 0; i < 4; ++i) ka[i] = *(const f32x4*)(kp + i * 4);
    }

    f32x4 sacc[4];
#pragma unroll
    for (int jb = 0; jb < 4; ++jb) sacc[jb] = (f32x4){0.f, 0.f, 0.f, 0.f};
#pragma unroll
    for (int kh = 0; kh < 2; ++kh) {
#pragma unroll
      for (int jb = 0; jb < 4; ++jb) {
        bf16x8 kf = *(const bf16x8*)(&kbuf[cur][((jb * 16 + lr) * 64 + kh * 32 + lg * 8) ^ asw]);
        sacc[jb] = __builtin_amdgcn_mfma_f32_16x16x32_bf16(kf, qf[kh], sacc[jb], 0, 0, 0);
      }
    }

    // p~*rl -> bf16 -> pscr (lane's row lr is its own: rlA correct)
    const bool diag = (kt == NT - 1);
#pragma unroll
    for (int jb = 0; jb < 4; ++jb) {
      short4 ps;
#pragma unroll
      for (int r = 0; r < 4; ++r) {
        const int jgl = kt * 64 + jb * 16 + lg * 4 + r;
        float pt = exp2_fast(sacc[jb][r]);
        if (diag && jgl > igl) pt = 0.f;
        ((short*)&ps)[r] = f2bf(pt * rlA);
      }
      *(short4*)(&pscr[w][(lr * 64 + jb * 16 + lg * 4) ^ asw]) = ps;
    }

    // transpose-read + NT store: one instruction = 4 rows x 256B-contiguous runs
#pragma unroll
    for (int it = 0; it < 4; ++it) {
      const int row = it * 4 + i2;
      short4 pv4 = *(const short4*)(&pscr[w][(row * 64 + c2) ^ ((row & 7) << 3)]);
      f32x4 av = {bf2f((unsigned short)pv4.x), bf2f((unsigned short)pv4.y),
                  bf2f((unsigned short)pv4.z), bf2f((unsigned short)pv4.w)};
      __builtin_nontemporal_store(
          av, (f32x4*)(a_base + (size_t)(qrow0 + w * 16 + row) * S + kt * 64 + c2));
    }

    if (kt + 1 < NT) {
      bf16x8 kb;
#pragma unroll
      for (int e = 0; e < 4; ++e) { kb[e] = f2bf(ka[0][e]); kb[e + 4] = f2bf(ka[1][e]); }
      *(bf16x8*)(&kbuf[cur ^ 1][(krow * 64 + kc) ^ kswz]) = kb;
#pragma unroll
      for (int e = 0; e < 4; ++e) { kb[e] = f2bf(ka[2][e]); kb[e + 4] = f2bf(ka[3][e]); }
      *(bf16x8*)(&kbuf[cur ^ 1][(krow * 64 + kc + 8) ^ kswz]) = kb;
    }
    bar_lds();
  }
}

extern "C" void kernel_launch(void* const* d_in, const int* in_sizes, int n_in,
                              void* d_out, int out_size, void* d_ws, size_t ws_size,
                              hipStream_t stream) {
  const float* q = (const float*)d_in[0];
  const float* k = (const float*)d_in[1];
  const float* v = (const float*)d_in[2];
  float* out = (float*)d_out;
  attn_fused<<<dim3(2048), dim3(256), 0, stream>>>(q, k, v, out);
}

// Round 21
// 268.083 us; speedup vs baseline: 1.0113x; 1.0113x over previous
//
#include <hip/hip_runtime.h>
#include <hip/hip_bf16.h>

namespace {
constexpr int S = 2048;
constexpr int D = 64;
constexpr float QSCALE = 0.18033688011112042f;  // (1/sqrt(64)) * log2(e)

using f32x4 = __attribute__((ext_vector_type(4))) float;
using bf16x8 = __attribute__((ext_vector_type(8))) short;

__device__ __forceinline__ short f2bf(float f) {
  return __builtin_bit_cast(short, __float2bfloat16(f));  // native RNE cvt
}
__device__ __forceinline__ float bf2f(unsigned short s) {
  return __builtin_bit_cast(float, (unsigned)s << 16);
}
#if __has_builtin(__builtin_amdgcn_exp2f)
__device__ __forceinline__ float exp2_fast(float x) { return __builtin_amdgcn_exp2f(x); }
#else
__device__ __forceinline__ float exp2_fast(float x) { return exp2f(x); }
#endif

__device__ __forceinline__ void bar_lds() {  // lgkm-only barrier: vmem prefetch stays in flight
  asm volatile("s_waitcnt lgkmcnt(0)" ::: "memory");
  __builtin_amdgcn_s_barrier();
}
}  // namespace

// FINAL (r19, 268.7 us): fused causal attention emitting O and the full
// normalized attention matrix.
//   - zero-fill a[:, NT*64:) first as 256B-contiguous NT runs (stores drain
//     under everyone's compute phase)
//   - loop A: QK^T (MFMA bf16, swapped operands so lane owns its q-row) ->
//     exp2 -> l accumulation; PV via per-wave pscr LDS round-trip
//   - loop B: QK^T recompute (K is L2-hot), p~*rl -> bf16 -> pscr transpose ->
//     256B-contiguous NT stores of fp32 a
// 40KB LDS -> 4 blocks/CU; XCD-chunked block map with long/short qt interleave.
__global__ __launch_bounds__(256, 4) void attn_fused(const float* __restrict__ qg,
                                                     const float* __restrict__ kg,
                                                     const float* __restrict__ vg,
                                                     float* __restrict__ outg) {
  __shared__ short kbuf[2][64 * 64];   // K[j][d] bf16, XOR-swizzled, dbuf
  __shared__ short vbuf[2][64 * 64];   // V^T[d][j] bf16, XOR-swizzled, dbuf
  __shared__ short pscr[4][16 * 64];   // per-wave p~ redistribution scratch

  const int tid = threadIdx.x;
  const int w = tid >> 6, lane = tid & 63, lg = lane >> 4, lr = lane & 15;

  // XCD-chunked block map + long/short qt interleave for co-resident balance
  const int u = blockIdx.x;
  const int logical = (u & 7) * 256 + (u >> 3);  // 2048 % 8 == 0
  const int bh = logical >> 5;
  const int uu = logical & 31;
  const int qt = (uu & 1) ? (31 - (uu >> 1)) : (uu >> 1);
  const int qrow0 = qt * 64;
  const int NT = qt + 1;

  const size_t bh_off = (size_t)bh * S * D;
  float* const og = outg;
  float* const a_base = outg + (size_t)64 * S * D + (size_t)bh * S * S;
  const int asw = (lr & 7) << 3;

  const int igl = qrow0 + w * 16 + lr;  // this lane's q-row (QK col i / p row)

  // ---- zero tiles (j >= NT*64) FIRST, 256B-contiguous runs per instruction ----
  {
    const int zrow = tid >> 4;           // 0..15
    const int zcol = (tid & 15) * 4;     // 16 lanes x f32x4 = 256B run
    const f32x4 z = {0.f, 0.f, 0.f, 0.f};
    for (int zt = NT; zt < S / 64; ++zt) {
#pragma unroll
      for (int rg = 0; rg < 4; ++rg) {
        __builtin_nontemporal_store(
            z, (f32x4*)(a_base + (size_t)(qrow0 + rg * 16 + zrow) * S + zt * 64 + zcol));
      }
    }
  }

  // ---- Q B-fragment (col i = lr-row of this wave, k = d), QSCALE folded ----
  bf16x8 qf[2];
#pragma unroll
  for (int kh = 0; kh < 2; ++kh) {
    const float* qp = qg + bh_off + (size_t)igl * D + kh * 32 + lg * 8;
    f32x4 x0 = *(const f32x4*)(qp);
    f32x4 x1 = *(const f32x4*)(qp + 4);
    bf16x8 f;
#pragma unroll
    for (int e = 0; e < 4; ++e) {
      f[e] = f2bf(x0[e] * QSCALE);
      f[e + 4] = f2bf(x1[e] * QSCALE);
    }
    qf[kh] = f;
  }

  const int krow = tid >> 2, kc = (tid & 3) * 16;
  const int kswz = (krow & 7) << 3;
  const int vj = tid & 63, vd0 = (tid >> 6) * 16;

  // =========================== loop A: l + O(unnormalized) ===========================
  f32x4 ka[4], va[4];
  {
    const float* kp = kg + bh_off + (size_t)krow * D + kc;
#pragma unroll
    for (int i = 0; i < 4; ++i) ka[i] = *(const f32x4*)(kp + i * 4);
    const float* vp = vg + bh_off + (size_t)vj * D + vd0;
#pragma unroll
    for (int i = 0; i < 4; ++i) va[i] = *(const f32x4*)(vp + i * 4);
  }
  {  // stage tile 0
    bf16x8 kb;
#pragma unroll
    for (int e = 0; e < 4; ++e) { kb[e] = f2bf(ka[0][e]); kb[e + 4] = f2bf(ka[1][e]); }
    *(bf16x8*)(&kbuf[0][(krow * 64 + kc) ^ kswz]) = kb;
#pragma unroll
    for (int e = 0; e < 4; ++e) { kb[e] = f2bf(ka[2][e]); kb[e + 4] = f2bf(ka[3][e]); }
    *(bf16x8*)(&kbuf[0][(krow * 64 + kc + 8) ^ kswz]) = kb;
#pragma unroll
    for (int i = 0; i < 4; ++i)
#pragma unroll
      for (int e = 0; e < 4; ++e) {
        const int d = vd0 + i * 4 + e;
        vbuf[0][(d * 64 + vj) ^ ((d & 7) << 3)] = f2bf(va[i][e]);
      }
  }
  bar_lds();

  float l_acc = 0.f;
  f32x4 oacc[4];
#pragma unroll
  for (int dg = 0; dg < 4; ++dg) oacc[dg] = (f32x4){0.f, 0.f, 0.f, 0.f};

  for (int kt = 0; kt < NT; ++kt) {
    const int cur = kt & 1;
    if (kt + 1 < NT) {  // prefetch next K/V tiles into regs
      const float* kp = kg + bh_off + (size_t)((kt + 1) * 64 + krow) * D + kc;
#pragma unroll
      for (int i = 0; i < 4; ++i) ka[i] = *(const f32x4*)(kp + i * 4);
      const float* vp = vg + bh_off + (size_t)((kt + 1) * 64 + vj) * D + vd0;
#pragma unroll
      for (int i = 0; i < 4; ++i) va[i] = *(const f32x4*)(vp + i * 4);
    }

    // QK^T: D[j][i], lane col i = lr, rows j = jb*16 + lg*4 + r
    f32x4 sacc[4];
#pragma unroll
    for (int jb = 0; jb < 4; ++jb) sacc[jb] = (f32x4){0.f, 0.f, 0.f, 0.f};
#pragma unroll
    for (int kh = 0; kh < 2; ++kh) {
#pragma unroll
      for (int jb = 0; jb < 4; ++jb) {
        bf16x8 kf = *(const bf16x8*)(&kbuf[cur][((jb * 16 + lr) * 64 + kh * 32 + lg * 8) ^ asw]);
        sacc[jb] = __builtin_amdgcn_mfma_f32_16x16x32_bf16(kf, qf[kh], sacc[jb], 0, 0, 0);
      }
    }

    // p~ = exp2(s) (masked on diagonal tile); accumulate l; pscr for PV
    const bool diag = (kt == NT - 1);
#pragma unroll
    for (int jb = 0; jb < 4; ++jb) {
      short4 ps;
#pragma unroll
      for (int r = 0; r < 4; ++r) {
        const int jgl = kt * 64 + jb * 16 + lg * 4 + r;
        float pt = exp2_fast(sacc[jb][r]);
        if (diag && jgl > igl) pt = 0.f;
        l_acc += pt;
        ((short*)&ps)[r] = f2bf(pt);
      }
      *(short4*)(&pscr[w][(lr * 64 + jb * 16 + lg * 4) ^ asw]) = ps;
    }

    // PV: O[i][d] += p~ V (pscr same-wave)
#pragma unroll
    for (int ks = 0; ks < 2; ++ks) {
      bf16x8 pa = *(const bf16x8*)(&pscr[w][(lr * 64 + ks * 32 + lg * 8) ^ asw]);
#pragma unroll
      for (int dg = 0; dg < 4; ++dg) {
        bf16x8 vb = *(const bf16x8*)(&vbuf[cur][((dg * 16 + lr) * 64 + ks * 32 + lg * 8) ^ asw]);
        oacc[dg] = __builtin_amdgcn_mfma_f32_16x16x32_bf16(pa, vb, oacc[dg], 0, 0, 0);
      }
    }

    if (kt + 1 < NT) {  // stage next tile into the other buffers
      bf16x8 kb;
#pragma unroll
      for (int e = 0; e < 4; ++e) { kb[e] = f2bf(ka[0][e]); kb[e + 4] = f2bf(ka[1][e]); }
      *(bf16x8*)(&kbuf[cur ^ 1][(krow * 64 + kc) ^ kswz]) = kb;
#pragma unroll
      for (int e = 0; e < 4; ++e) { kb[e] = f2bf(ka[2][e]); kb[e + 4] = f2bf(ka[3][e]); }
      *(bf16x8*)(&kbuf[cur ^ 1][(krow * 64 + kc + 8) ^ kswz]) = kb;
#pragma unroll
      for (int i = 0; i < 4; ++i)
#pragma unroll
        for (int e = 0; e < 4; ++e) {
          const int d = vd0 + i * 4 + e;
          vbuf[cur ^ 1][(d * 64 + vj) ^ ((d & 7) << 3)] = f2bf(va[i][e]);
        }
    }
    bar_lds();
  }

  // ---- rl: reduce partials across lg; lane then holds rl for its row igl ----
  l_acc += __shfl_xor(l_acc, 16, 64);
  l_acc += __shfl_xor(l_acc, 32, 64);
  const float rlA = 1.f / l_acc;

  // O rescale needs rl at rows w*16+lg*4+r: bounce via per-wave pscr region
  {
    float* const rlv = (float*)(&pscr[w][0]);
    if (lane < 16) rlv[lr] = rlA;
    asm volatile("s_waitcnt lgkmcnt(0)" ::: "memory");  // same-wave write->read
#pragma unroll
    for (int dg = 0; dg < 4; ++dg) {
#pragma unroll
      for (int r = 0; r < 4; ++r) {
        const int il = qrow0 + w * 16 + lg * 4 + r;
        og[bh_off + (size_t)il * D + dg * 16 + lr] = oacc[dg][r] * rlv[lg * 4 + r];
      }
    }
  }

  // ====== loop B: normalized a via pscr transpose -> 256B-contiguous NT stores ======
  {
    const float* kp = kg + bh_off + (size_t)krow * D + kc;
#pragma unroll
    for (int i = 0; i < 4; ++i) ka[i] = *(const f32x4*)(kp + i * 4);
  }
  {  // stage tile 0 (A-loop reads of kbuf[0] finished at A's last barrier)
    bf16x8 kb;
#pragma unroll
    for (int e = 0; e < 4; ++e) { kb[e] = f2bf(ka[0][e]); kb[e + 4] = f2bf(ka[1][e]); }
    *(bf16x8*)(&kbuf[0][(krow * 64 + kc) ^ kswz]) = kb;
#pragma unroll
    for (int e = 0; e < 4; ++e) { kb[e] = f2bf(ka[2][e]); kb[e + 4] = f2bf(ka[3][e]); }
    *(bf16x8*)(&kbuf[0][(krow * 64 + kc + 8) ^ kswz]) = kb;
  }
  bar_lds();

  const int i2 = (lane >> 4);        // row-subgroup for the store phase
  const int c2 = (lane & 15) * 4;    // 16 lanes x f32x4 = full 64-col tile row
  for (int kt = 0; kt < NT; ++kt) {
    const int cur = kt & 1;
    if (kt + 1 < NT) {  // prefetch next K tile (issued BEFORE this tile's stores)
      const float* kp = kg + bh_off + (size_t)((kt + 1) * 64 + krow) * D + kc;
#pragma unroll
      for (int i = 0; i < 4; ++i) ka[i] = *(const f32x4*)(kp + i * 4);
    }

    f32x4 sacc[4];
#pragma unroll
    for (int jb = 0; jb < 4; ++jb) sacc[jb] = (f32x4){0.f, 0.f, 0.f, 0.f};
#pragma unroll
    for (int kh = 0; kh < 2; ++kh) {
#pragma unroll
      for (int jb = 0; jb < 4; ++jb) {
        bf16x8 kf = *(const bf16x8*)(&kbuf[cur][((jb * 16 + lr) * 64 + kh * 32 + lg * 8) ^ asw]);
        sacc[jb] = __builtin_amdgcn_mfma_f32_16x16x32_bf16(kf, qf[kh], sacc[jb], 0, 0, 0);
      }
    }

    // p~*rl -> bf16 -> pscr (lane's row lr is its own: rlA correct)
    const bool diag = (kt == NT - 1);
#pragma unroll
    for (int jb = 0; jb < 4; ++jb) {
      short4 ps;
#pragma unroll
      for (int r = 0; r < 4; ++r) {
        const int jgl = kt * 64 + jb * 16 + lg * 4 + r;
        float pt = exp2_fast(sacc[jb][r]);
        if (diag && jgl > igl) pt = 0.f;
        ((short*)&ps)[r] = f2bf(pt * rlA);
      }
      *(short4*)(&pscr[w][(lr * 64 + jb * 16 + lg * 4) ^ asw]) = ps;
    }

    // transpose-read + NT store: one instruction = 4 rows x 256B-contiguous runs
#pragma unroll
    for (int it = 0; it < 4; ++it) {
      const int row = it * 4 + i2;
      short4 pv4 = *(const short4*)(&pscr[w][(row * 64 + c2) ^ ((row & 7) << 3)]);
      f32x4 av = {bf2f((unsigned short)pv4.x), bf2f((unsigned short)pv4.y),
                  bf2f((unsigned short)pv4.z), bf2f((unsigned short)pv4.w)};
      __builtin_nontemporal_store(
          av, (f32x4*)(a_base + (size_t)(qrow0 + w * 16 + row) * S + kt * 64 + c2));
    }

    if (kt + 1 < NT) {
      bf16x8 kb;
#pragma unroll
      for (int e = 0; e < 4; ++e) { kb[e] = f2bf(ka[0][e]); kb[e + 4] = f2bf(ka[1][e]); }
      *(bf16x8*)(&kbuf[cur ^ 1][(krow * 64 + kc) ^ kswz]) = kb;
#pragma unroll
      for (int e = 0; e < 4; ++e) { kb[e] = f2bf(ka[2][e]); kb[e + 4] = f2bf(ka[3][e]); }
      *(bf16x8*)(&kbuf[cur ^ 1][(krow * 64 + kc + 8) ^ kswz]) = kb;
    }
    bar_lds();
  }
}

extern "C" void kernel_launch(void* const* d_in, const int* in_sizes, int n_in,
                              void* d_out, int out_size, void* d_ws, size_t ws_size,
                              hipStream_t stream) {
  const float* q = (const float*)d_in[0];
  const float* k = (const float*)d_in[1];
  const float* v = (const float*)d_in[2];
  float* out = (float*)d_out;
  attn_fused<<<dim3(2048), dim3(256), 0, stream>>>(q, k, v, out);
}